// Round 15
// baseline (444.605 us; speedup 1.0000x reference)
//
#include <hip/hip_runtime.h>
#include <hip/hip_bf16.h>

#define NN 50000
#define NE 800000
#define DD 128
#define NCLS 40
#define NBK ((NN + 255) >> 8)      // 196 dst-buckets of 256 nodes
#define EPB 1024                   // edges per k_part block (4/thread)
#define PB ((NE + EPB - 1) / EPB)  // 782 partition blocks
#define CVB ((NN * DD / 4) / 256)  // 6250 cvt blocks
#define WB 384                     // weight-convert blocks (192 units x 2 halves)
#define SEMAX 5120                 // max edges per bucket (mean 4081, sd 64)

typedef _Float16 f16x8 __attribute__((ext_vector_type(8)));  // 8 f16 (4 VGPRs)
typedef _Float16 f16x4 __attribute__((ext_vector_type(4)));
typedef float f32x4 __attribute__((ext_vector_type(4)));     // MFMA acc

__device__ __forceinline__ unsigned int pack2h(_Float16 a, _Float16 b) {
    union { _Float16 h[2]; unsigned int u; } c;
    c.h[0] = a; c.h[1] = b;
    return c.u;
}
__device__ __forceinline__ void unpack2h(unsigned int p, float& a, float& b) {
    union { unsigned int u; _Float16 h[2]; } c;
    c.u = p;
    a = (float)c.h[0]; b = (float)c.h[1];
}

// ---------------------------------------------------------------------------
// Mega front kernel.
//   Blocks [0,PB):            LDS bucket-sort of 1024 edges -> dense chunk
//   Blocks [PB,PB+CVB):       x fp32 -> f16 hi plane
//   Blocks [PB+CVB,+WB):      all 3 layers' B -> MFMA-fragment-major hi/lo
__global__ void k_front(const int* __restrict__ ei, int* __restrict__ cellcnt,
                        int* __restrict__ celloff, unsigned int* __restrict__ pairs,
                        const float* __restrict__ x, unsigned short* __restrict__ xh,
                        const float* __restrict__ w1l, const float* __restrict__ w1r,
                        const float* __restrict__ w2l, const float* __restrict__ w2r,
                        const float* __restrict__ w3l, const float* __restrict__ w3r,
                        unsigned short* __restrict__ bt1h, unsigned short* __restrict__ bt1l,
                        unsigned short* __restrict__ bt2h, unsigned short* __restrict__ bt2l,
                        unsigned short* __restrict__ bt3h, unsigned short* __restrict__ bt3l) {
    if (blockIdx.x >= PB + CVB) {
        // ---- weight conversion ----
        int idx = blockIdx.x - (PB + CVB);
        int w = idx >> 1, half = idx & 1;
        int ks = w & 7, tmp = w >> 3;
        int nt = tmp & 7, layer = tmp >> 3;
        const int NT = (layer == 2) ? 3 : 8;
        const int NC = (layer == 2) ? NCLS : DD;
        if (nt >= NT) return;
        const float* wl = (layer == 0) ? w1l : (layer == 1) ? w2l : w3l;
        const float* wr = (layer == 0) ? w1r : (layer == 1) ? w2r : w3r;
        unsigned short* bh = (layer == 0) ? bt1h : (layer == 1) ? bt2h : bt3h;
        unsigned short* bl = (layer == 0) ? bt1l : (layer == 1) ? bt2l : bt3l;
        int t = threadIdx.x;
        int j = t & 7, lane = (t >> 3) + half * 32;
        int row = nt * 16 + (lane & 15);          // output column n
        int k = ks * 32 + (lane >> 4) * 8 + j;    // K position in [Wl;Wr]
        float v = 0.f;
        if (row < NC)
            v = (k < 128) ? wl[(size_t)k * NC + row] : wr[(size_t)(k - 128) * NC + row];
        _Float16 h = (_Float16)v;
        _Float16 l = (_Float16)(v - (float)h);
        size_t o = ((size_t)(ks * NT + nt) * 64 + lane) * 8 + j;
        union { _Float16 f; unsigned short u; } ch, cl;
        ch.f = h; cl.f = l;
        bh[o] = ch.u;
        bl[o] = cl.u;
        return;
    }
    if (blockIdx.x >= PB) {
        // ---- x conversion ----
        int i = (blockIdx.x - PB) * 256 + threadIdx.x;
        float4 v = ((const float4*)x)[i];
        f16x4 h;
        h[0] = (_Float16)v.x; h[1] = (_Float16)v.y;
        h[2] = (_Float16)v.z; h[3] = (_Float16)v.w;
        *(f16x4*)(xh + (size_t)i * 4) = h;
        return;
    }
    // ---- edge partition ----
    __shared__ int hist[NBK];
    __shared__ int s[256];
    __shared__ unsigned int sE[EPB];
    __shared__ int nz;
    const int t = threadIdx.x, blk = blockIdx.x;
    const int e0 = blk * EPB;
    if (t == 0) nz = 0;
    for (int i = t; i < NBK; i += 256) hist[i] = 0;
    __syncthreads();
    int any = 0;
    for (int i = t; i < EPB; i += 256)
        if (ei[2 * e0 + 2 * i + 1] != 0) any = 1;
    if (any) atomicOr(&nz, 1);
    __syncthreads();
    const int is64 = (nz == 0);
    unsigned int v[EPB / 256];
    int eb[EPB / 256], er[EPB / 256];
#pragma unroll
    for (int j = 0; j < EPB / 256; ++j) {
        int e = e0 + j * 256 + t;
        if (e < NE) {
            int sv, d;
            if (is64) { sv = ei[2 * e]; d = ei[2 * (NE + e)]; }
            else      { sv = ei[e];     d = ei[NE + e]; }
            v[j] = ((unsigned)sv << 16) | (unsigned)d;
            eb[j] = d >> 8;
            er[j] = atomicAdd(&hist[eb[j]], 1);
        } else {
            eb[j] = -1;
        }
    }
    __syncthreads();
    int hv = (t < NBK) ? hist[t] : 0;
    s[t] = hv;
    __syncthreads();
#pragma unroll
    for (int off = 1; off < 256; off <<= 1) {
        int u = (t >= off) ? s[t - off] : 0;
        __syncthreads();
        s[t] += u;
        __syncthreads();
    }
#pragma unroll
    for (int j = 0; j < EPB / 256; ++j)
        if (eb[j] >= 0) sE[s[eb[j]] - hist[eb[j]] + er[j]] = v[j];
    __syncthreads();
    ((uint4*)(pairs + (size_t)blk * EPB))[t] = ((const uint4*)sE)[t];
    for (int i = t; i < NBK; i += 256) {
        cellcnt[(size_t)i * PB + blk] = hist[i];
        celloff[(size_t)i * PB + blk] = s[i] - hist[i];
    }
}

// Bucket totals: 196 blocks, block b reduces its (coalesced) cellcnt row.
__global__ void k_scan_ba(const int* __restrict__ cellcnt, int* __restrict__ bsum) {
    __shared__ int red[256];
    int b = blockIdx.x, t = threadIdx.x;
    int acc = 0;
    for (int i = t; i < PB; i += 256) acc += cellcnt[(size_t)b * PB + i];
    red[t] = acc;
    __syncthreads();
#pragma unroll
    for (int off = 128; off > 0; off >>= 1) {
        if (t < off) red[t] += red[t + off];
        __syncthreads();
    }
    if (t == 0) bsum[b] = red[0];
}

// Exclusive scan of 196 bucket sums -> bbase, grand total -> row_ptr[NN].
__global__ void k_scan_bb(const int* __restrict__ bsum, int* __restrict__ bbase,
                          int* __restrict__ row_ptr) {
    __shared__ int s[256];
    int t = threadIdx.x;
    int v = (t < NBK) ? bsum[t] : 0;
    s[t] = v;
    __syncthreads();
#pragma unroll
    for (int off = 1; off < 256; off <<= 1) {
        int u = (t >= off) ? s[t - off] : 0;
        __syncthreads();
        s[t] += u;
        __syncthreads();
    }
    if (t < NBK) bbase[t] = s[t] - v;  // exclusive
    if (t == 255) { bbase[NBK] = s[255]; row_ptr[NN] = s[255]; }
}

// Phase 2: one 512-thread block per bucket; per-node histogram + prefix ->
// row_ptr, then LDS-cursor scatter into the bucket's contiguous srcs run.
__global__ void k_fill2(const unsigned int* __restrict__ pairs,
                        const int* __restrict__ cellcnt,
                        const int* __restrict__ celloff,
                        const int* __restrict__ bbase,
                        int* __restrict__ row_ptr, int* __restrict__ srcs) {
    __shared__ unsigned int sE[SEMAX];
    __shared__ int hist[256];
    __shared__ int cur[256];
    __shared__ int scnt;
    const int b = blockIdx.x, t = threadIdx.x;
    if (t == 0) scnt = 0;
    if (t < 256) hist[t] = 0;
    __syncthreads();
    for (int blk = t; blk < PB; blk += 512) {
        int cnt = cellcnt[(size_t)b * PB + blk];
        if (cnt) {
            int off = celloff[(size_t)b * PB + blk];
            int base = atomicAdd(&scnt, cnt);
            if (base + cnt <= SEMAX) {
                const unsigned int* pp = pairs + (size_t)blk * EPB + off;
                for (int j = 0; j < cnt; ++j) {
                    unsigned int v = pp[j];
                    sE[base + j] = v;
                    atomicAdd(&hist[v & 255u], 1);
                }
            }
        }
    }
    __syncthreads();
    int h = (t < 256) ? hist[t] : 0;
    if (t < 256) cur[t] = h;
    __syncthreads();
#pragma unroll
    for (int off = 1; off < 256; off <<= 1) {
        int u = (t >= off && t < 256) ? cur[t - off] : 0;
        __syncthreads();
        if (t < 256) cur[t] += u;
        __syncthreads();
    }
    if (t < 256) {
        int node = (b << 8) + t;
        int base = bbase[b] + cur[t] - h;
        if (node < NN) row_ptr[node] = base;
        cur[t] = base;
    }
    __syncthreads();
    int total = min(scnt, SEMAX);
    for (int i = t; i < total; i += 512) {
        unsigned int v = sE[i];
        int pos = atomicAdd(&cur[v & 255u], 1);
        srcs[pos] = (int)(v >> 16);
    }
}

// ---------------------------------------------------------------------------
// Fused agg + GEMM. Block = 4 waves = 64 rows.
// Phase 1: each wave mean-aggregates its 16 nodes (hi-plane gather, 8-deep
//          ILP) into LDS tile sA (f16, pitch 136 -> conflict-free frag reads).
// Phase 2: f16 MFMA GEMM; A1 (agg, ks<4) from sA via ds_read_b128, A2 (self,
//          ks>=4) from global inh; B hi+lo staged in LDS fragment-major.
//          acc += Ah*Bh + Ah*Bl per (ks,n).
template <int NT, int KPS, bool PACKOUT>
__launch_bounds__(256, 3)
__global__ void k_fused(const unsigned short* __restrict__ inh,
                        const int* __restrict__ row_ptr, const int* __restrict__ srcs,
                        const unsigned short* __restrict__ Bthf,
                        const unsigned short* __restrict__ Btlf,
                        const float* __restrict__ bias, float* __restrict__ outf,
                        unsigned short* __restrict__ outh, const int NC) {
    constexpr int STAGE_ELEMS = KPS * NT * 64 * 8;
    constexpr int STAGE_U4 = STAGE_ELEMS / 8;
    constexpr int APITCH = 136;  // shorts; 68 words -> 2-way bank alias (free)
    __shared__ unsigned short sBh[STAGE_ELEMS];
    __shared__ unsigned short sBl[STAGE_ELEMS];
    __shared__ unsigned short sA[64 * APITCH];

    const int tid = threadIdx.x;
    const int wave = tid >> 6, lane = tid & 63;
    const int quad = lane >> 4, mr = lane & 15;
    const int m0 = blockIdx.x * 64;
    const unsigned int* in32 = (const unsigned int*)inh;

    // ---- Phase 1: aggregate this block's 64 nodes into sA
    for (int i = 0; i < 16; ++i) {
        int node = m0 + wave * 16 + i;
        unsigned int packed = 0;
        if (node < NN) {
            int b = row_ptr[node], e = row_ptr[node + 1];
            float a0 = 0.f, a1 = 0.f;
            int it = b;
            for (; it + 7 < e; it += 8) {
                unsigned int p0 = in32[(size_t)srcs[it + 0] * 64 + lane];
                unsigned int p1 = in32[(size_t)srcs[it + 1] * 64 + lane];
                unsigned int p2 = in32[(size_t)srcs[it + 2] * 64 + lane];
                unsigned int p3 = in32[(size_t)srcs[it + 3] * 64 + lane];
                unsigned int p4 = in32[(size_t)srcs[it + 4] * 64 + lane];
                unsigned int p5 = in32[(size_t)srcs[it + 5] * 64 + lane];
                unsigned int p6 = in32[(size_t)srcs[it + 6] * 64 + lane];
                unsigned int p7 = in32[(size_t)srcs[it + 7] * 64 + lane];
                float u0, u1;
                unpack2h(p0, u0, u1); a0 += u0; a1 += u1;
                unpack2h(p1, u0, u1); a0 += u0; a1 += u1;
                unpack2h(p2, u0, u1); a0 += u0; a1 += u1;
                unpack2h(p3, u0, u1); a0 += u0; a1 += u1;
                unpack2h(p4, u0, u1); a0 += u0; a1 += u1;
                unpack2h(p5, u0, u1); a0 += u0; a1 += u1;
                unpack2h(p6, u0, u1); a0 += u0; a1 += u1;
                unpack2h(p7, u0, u1); a0 += u0; a1 += u1;
            }
            for (; it < e; ++it) {
                unsigned int p = in32[(size_t)srcs[it] * 64 + lane];
                float u0, u1;
                unpack2h(p, u0, u1); a0 += u0; a1 += u1;
            }
            int deg = e - b;
            float inv = 1.0f / (float)(deg > 0 ? deg : 1);
            packed = pack2h((_Float16)(a0 * inv), (_Float16)(a1 * inv));
        }
        *(unsigned int*)(sA + (size_t)(wave * 16 + i) * APITCH + lane * 2) = packed;
    }
    __syncthreads();

    // ---- Phase 2: GEMM
    const int row = m0 + wave * 16 + mr;
    const bool rok = row < NN;
    f32x4 acc[NT] = {};
    const f16x8 zero = {};

    auto aload = [&](int ks) -> f16x8 {
        const int ko = ((ks * 32) & 127) + quad * 8;
        if (ks < 4)
            return *(const f16x8*)(sA + (size_t)(wave * 16 + mr) * APITCH + ko);
        return rok ? *(const f16x8*)(inh + (size_t)row * 128 + ko) : zero;
    };

    f16x8 cah = aload(0), pah;

#pragma unroll
    for (int s = 0; s < 8 / KPS; ++s) {
        const uint4* gh = (const uint4*)(Bthf + (size_t)s * STAGE_ELEMS);
        const uint4* gl = (const uint4*)(Btlf + (size_t)s * STAGE_ELEMS);
        uint4* lh = (uint4*)sBh;
        uint4* ll = (uint4*)sBl;
        if (s) __syncthreads();
        for (int i = tid; i < STAGE_U4; i += 256) {
            lh[i] = gh[i];
            ll[i] = gl[i];
        }
        __syncthreads();

#pragma unroll
        for (int kl = 0; kl < KPS; ++kl) {
            const int ks = s * KPS + kl;
            if (ks < 7) pah = aload(ks + 1);
#pragma unroll
            for (int n = 0; n < NT; ++n) {
                const int fo = ((kl * NT + n) * 64 + lane) * 8;
                f16x8 bh = *(const f16x8*)(sBh + fo);
                f16x8 bl = *(const f16x8*)(sBl + fo);
                acc[n] = __builtin_amdgcn_mfma_f32_16x16x32_f16(cah, bh, acc[n], 0, 0, 0);
                acc[n] = __builtin_amdgcn_mfma_f32_16x16x32_f16(cah, bl, acc[n], 0, 0, 0);
            }
            cah = pah;
        }
    }

    // Epilogue. C/D layout: col = lane&15, row = quad*4 + reg.
#pragma unroll
    for (int n = 0; n < NT; ++n) {
        int col = n * 16 + mr;
        float bv = (col < NC) ? bias[col] : 0.f;
#pragma unroll
        for (int r = 0; r < 4; ++r) {
            int orow = m0 + wave * 16 + quad * 4 + r;
            if (orow < NN && col < NC) {
                float v = acc[n][r] + bv;
                v = v > 0.f ? v : 0.f;
                if (PACKOUT) {
                    union { _Float16 f; unsigned short u; } ch;
                    ch.f = (_Float16)v;
                    outh[(size_t)orow * 128 + col] = ch.u;
                } else {
                    outf[(size_t)orow * NC + col] = v;
                }
            }
        }
    }
}

// ---------------------------------------------------------------------------
extern "C" void kernel_launch(void* const* d_in, const int* in_sizes, int n_in,
                              void* d_out, int out_size, void* d_ws, size_t ws_size,
                              hipStream_t stream) {
    const float* x    = (const float*)d_in[0];
    const int*   ei   = (const int*)d_in[1];
    const float* w1_l = (const float*)d_in[2];
    const float* w1_r = (const float*)d_in[3];
    const float* b1   = (const float*)d_in[4];
    const float* w2_l = (const float*)d_in[5];
    const float* w2_r = (const float*)d_in[6];
    const float* b2   = (const float*)d_in[7];
    const float* w3_l = (const float*)d_in[8];
    const float* w3_r = (const float*)d_in[9];
    const float* b3   = (const float*)d_in[10];
    float* out = (float*)d_out;

    char* w = (char*)d_ws;
    size_t off = 0;
    auto alloc = [&](size_t bytes) -> void* {
        void* p = w + off;
        off += (bytes + 255) / 256 * 256;
        return p;
    };
    int* row_ptr = (int*)alloc((size_t)(NN + 1) * 4);
    int* srcs    = (int*)alloc((size_t)NE * 4);
    int* cellcnt = (int*)alloc((size_t)NBK * PB * 4);
    int* celloff = (int*)alloc((size_t)NBK * PB * 4);
    int* bsum    = (int*)alloc((size_t)NBK * 4);
    int* bbase   = (int*)alloc((size_t)(NBK + 1) * 4);
    unsigned int* pairs = (unsigned int*)alloc((size_t)PB * EPB * 4);
    unsigned short* xh   = (unsigned short*)alloc((size_t)NN * DD * 2);  // also h2h
    unsigned short* h1h  = (unsigned short*)alloc((size_t)NN * DD * 2);
    unsigned short* bt1h = (unsigned short*)alloc((size_t)8 * 8 * 64 * 8 * 2);
    unsigned short* bt1l = (unsigned short*)alloc((size_t)8 * 8 * 64 * 8 * 2);
    unsigned short* bt2h = (unsigned short*)alloc((size_t)8 * 8 * 64 * 8 * 2);
    unsigned short* bt2l = (unsigned short*)alloc((size_t)8 * 8 * 64 * 8 * 2);
    unsigned short* bt3h = (unsigned short*)alloc((size_t)8 * 3 * 64 * 8 * 2);
    unsigned short* bt3l = (unsigned short*)alloc((size_t)8 * 3 * 64 * 8 * 2);
    unsigned short* h2h = xh;  // x dead after layer-1
    (void)ws_size;

    k_front<<<PB + CVB + WB, 256, 0, stream>>>(ei, cellcnt, celloff, pairs, x, xh,
                                               w1_l, w1_r, w2_l, w2_r, w3_l, w3_r,
                                               bt1h, bt1l, bt2h, bt2l, bt3h, bt3l);
    k_scan_ba<<<NBK, 256, 0, stream>>>(cellcnt, bsum);
    k_scan_bb<<<1, 256, 0, stream>>>(bsum, bbase, row_ptr);
    k_fill2<<<NBK, 512, 0, stream>>>(pairs, cellcnt, celloff, bbase, row_ptr, srcs);

    const int gmb = (NN + 63) / 64;   // 782
    k_fused<8, 2, true><<<gmb, 256, 0, stream>>>(xh, row_ptr, srcs, bt1h, bt1l,
                                                 b1, nullptr, h1h, DD);
    k_fused<8, 2, true><<<gmb, 256, 0, stream>>>(h1h, row_ptr, srcs, bt2h, bt2l,
                                                 b2, nullptr, h2h, DD);
    k_fused<3, 2, false><<<gmb, 256, 0, stream>>>(h2h, row_ptr, srcs, bt3h, bt3l,
                                                  b3, out, nullptr, NCLS);
}

// Round 16
// 276.928 us; speedup vs baseline: 1.6055x; 1.6055x over previous
//
#include <hip/hip_runtime.h>
#include <hip/hip_bf16.h>

#define NN 50000
#define NE 800000
#define DD 128
#define NCLS 40
#define NBK ((NN + 255) >> 8)      // 196 dst-buckets of 256 nodes
#define EPB 1024                   // edges per k_part block (4/thread)
#define PB ((NE + EPB - 1) / EPB)  // 782 partition blocks
#define CVB ((NN * DD / 4) / 256)  // 6250 cvt blocks
#define WB 384                     // weight-convert blocks (192 units x 2 halves)
#define SEMAX 5120                 // max edges per bucket (mean 4081, sd 64)

typedef _Float16 f16x8 __attribute__((ext_vector_type(8)));  // 8 f16 (4 VGPRs)
typedef _Float16 f16x4 __attribute__((ext_vector_type(4)));
typedef float f32x4 __attribute__((ext_vector_type(4)));     // MFMA acc

__device__ __forceinline__ unsigned int pack2h(_Float16 a, _Float16 b) {
    union { _Float16 h[2]; unsigned int u; } c;
    c.h[0] = a; c.h[1] = b;
    return c.u;
}
__device__ __forceinline__ void unpack2h(unsigned int p, float& a, float& b) {
    union { unsigned int u; _Float16 h[2]; } c;
    c.u = p;
    a = (float)c.h[0]; b = (float)c.h[1];
}

// ---------------------------------------------------------------------------
// Mega front kernel.
//   Blocks [0,PB):            LDS bucket-sort of 1024 edges -> dense chunk
//   Blocks [PB,PB+CVB):       x fp32 -> f16 hi plane
//   Blocks [PB+CVB,+WB):      all 3 layers' B -> MFMA-fragment-major hi/lo
__global__ void k_front(const int* __restrict__ ei, int* __restrict__ cellcnt,
                        int* __restrict__ celloff, unsigned int* __restrict__ pairs,
                        const float* __restrict__ x, unsigned short* __restrict__ xh,
                        const float* __restrict__ w1l, const float* __restrict__ w1r,
                        const float* __restrict__ w2l, const float* __restrict__ w2r,
                        const float* __restrict__ w3l, const float* __restrict__ w3r,
                        unsigned short* __restrict__ bt1h, unsigned short* __restrict__ bt1l,
                        unsigned short* __restrict__ bt2h, unsigned short* __restrict__ bt2l,
                        unsigned short* __restrict__ bt3h, unsigned short* __restrict__ bt3l) {
    if (blockIdx.x >= PB + CVB) {
        // ---- weight conversion ----
        int idx = blockIdx.x - (PB + CVB);
        int w = idx >> 1, half = idx & 1;
        int ks = w & 7, tmp = w >> 3;
        int nt = tmp & 7, layer = tmp >> 3;
        const int NT = (layer == 2) ? 3 : 8;
        const int NC = (layer == 2) ? NCLS : DD;
        if (nt >= NT) return;
        const float* wl = (layer == 0) ? w1l : (layer == 1) ? w2l : w3l;
        const float* wr = (layer == 0) ? w1r : (layer == 1) ? w2r : w3r;
        unsigned short* bh = (layer == 0) ? bt1h : (layer == 1) ? bt2h : bt3h;
        unsigned short* bl = (layer == 0) ? bt1l : (layer == 1) ? bt2l : bt3l;
        int t = threadIdx.x;
        int j = t & 7, lane = (t >> 3) + half * 32;
        int row = nt * 16 + (lane & 15);          // output column n
        int k = ks * 32 + (lane >> 4) * 8 + j;    // K position in [Wl;Wr]
        float v = 0.f;
        if (row < NC)
            v = (k < 128) ? wl[(size_t)k * NC + row] : wr[(size_t)(k - 128) * NC + row];
        _Float16 h = (_Float16)v;
        _Float16 l = (_Float16)(v - (float)h);
        size_t o = ((size_t)(ks * NT + nt) * 64 + lane) * 8 + j;
        union { _Float16 f; unsigned short u; } ch, cl;
        ch.f = h; cl.f = l;
        bh[o] = ch.u;
        bl[o] = cl.u;
        return;
    }
    if (blockIdx.x >= PB) {
        // ---- x conversion ----
        int i = (blockIdx.x - PB) * 256 + threadIdx.x;
        float4 v = ((const float4*)x)[i];
        f16x4 h;
        h[0] = (_Float16)v.x; h[1] = (_Float16)v.y;
        h[2] = (_Float16)v.z; h[3] = (_Float16)v.w;
        *(f16x4*)(xh + (size_t)i * 4) = h;
        return;
    }
    // ---- edge partition: LDS bucket-sort, dense chunk out ----
    __shared__ int hist[NBK];
    __shared__ int s[256];
    __shared__ unsigned int sE[EPB];
    __shared__ int nz;
    const int t = threadIdx.x, blk = blockIdx.x;
    const int e0 = blk * EPB;
    if (t == 0) nz = 0;
    for (int i = t; i < NBK; i += 256) hist[i] = 0;
    __syncthreads();
    int any = 0;
    for (int i = t; i < EPB; i += 256)
        if (ei[2 * e0 + 2 * i + 1] != 0) any = 1;
    if (any) atomicOr(&nz, 1);
    __syncthreads();
    const int is64 = (nz == 0);
    unsigned int v[EPB / 256];
    int eb[EPB / 256], er[EPB / 256];
#pragma unroll
    for (int j = 0; j < EPB / 256; ++j) {
        int e = e0 + j * 256 + t;
        if (e < NE) {
            int sv, d;
            if (is64) { sv = ei[2 * e]; d = ei[2 * (NE + e)]; }
            else      { sv = ei[e];     d = ei[NE + e]; }
            v[j] = ((unsigned)sv << 16) | (unsigned)d;
            eb[j] = d >> 8;
            er[j] = atomicAdd(&hist[eb[j]], 1);
        } else {
            eb[j] = -1;
        }
    }
    __syncthreads();
    int hv = (t < NBK) ? hist[t] : 0;
    s[t] = hv;
    __syncthreads();
#pragma unroll
    for (int off = 1; off < 256; off <<= 1) {
        int u = (t >= off) ? s[t - off] : 0;
        __syncthreads();
        s[t] += u;
        __syncthreads();
    }
#pragma unroll
    for (int j = 0; j < EPB / 256; ++j)
        if (eb[j] >= 0) sE[s[eb[j]] - hist[eb[j]] + er[j]] = v[j];
    __syncthreads();
    ((uint4*)(pairs + (size_t)blk * EPB))[t] = ((const uint4*)sE)[t];
    for (int i = t; i < NBK; i += 256) {
        cellcnt[(size_t)i * PB + blk] = hist[i];
        celloff[(size_t)i * PB + blk] = s[i] - hist[i];
    }
}

// Bucket totals: 196 blocks, block b reduces its (coalesced) cellcnt row.
__global__ void k_scan_ba(const int* __restrict__ cellcnt, int* __restrict__ bsum) {
    __shared__ int red[256];
    int b = blockIdx.x, t = threadIdx.x;
    int acc = 0;
    for (int i = t; i < PB; i += 256) acc += cellcnt[(size_t)b * PB + i];
    red[t] = acc;
    __syncthreads();
#pragma unroll
    for (int off = 128; off > 0; off >>= 1) {
        if (t < off) red[t] += red[t + off];
        __syncthreads();
    }
    if (t == 0) bsum[b] = red[0];
}

// Exclusive scan of 196 bucket sums -> bbase, grand total -> row_ptr[NN].
__global__ void k_scan_bb(const int* __restrict__ bsum, int* __restrict__ bbase,
                          int* __restrict__ row_ptr) {
    __shared__ int s[256];
    int t = threadIdx.x;
    int v = (t < NBK) ? bsum[t] : 0;
    s[t] = v;
    __syncthreads();
#pragma unroll
    for (int off = 1; off < 256; off <<= 1) {
        int u = (t >= off) ? s[t - off] : 0;
        __syncthreads();
        s[t] += u;
        __syncthreads();
    }
    if (t < NBK) bbase[t] = s[t] - v;  // exclusive
    if (t == 255) { bbase[NBK] = s[255]; row_ptr[NN] = s[255]; }
}

// Phase 2: one 512-thread block per bucket; per-node histogram + prefix ->
// row_ptr, then LDS-cursor scatter into the bucket's contiguous srcs run.
__global__ void k_fill2(const unsigned int* __restrict__ pairs,
                        const int* __restrict__ cellcnt,
                        const int* __restrict__ celloff,
                        const int* __restrict__ bbase,
                        int* __restrict__ row_ptr, int* __restrict__ srcs) {
    __shared__ unsigned int sE[SEMAX];
    __shared__ int hist[256];
    __shared__ int cur[256];
    __shared__ int scnt;
    const int b = blockIdx.x, t = threadIdx.x;
    if (t == 0) scnt = 0;
    if (t < 256) hist[t] = 0;
    __syncthreads();
    for (int blk = t; blk < PB; blk += 512) {
        int cnt = cellcnt[(size_t)b * PB + blk];
        if (cnt) {
            int off = celloff[(size_t)b * PB + blk];
            int base = atomicAdd(&scnt, cnt);
            if (base + cnt <= SEMAX) {
                const unsigned int* pp = pairs + (size_t)blk * EPB + off;
                for (int j = 0; j < cnt; ++j) {
                    unsigned int v = pp[j];
                    sE[base + j] = v;
                    atomicAdd(&hist[v & 255u], 1);
                }
            }
        }
    }
    __syncthreads();
    int h = (t < 256) ? hist[t] : 0;
    if (t < 256) cur[t] = h;
    __syncthreads();
#pragma unroll
    for (int off = 1; off < 256; off <<= 1) {
        int u = (t >= off && t < 256) ? cur[t - off] : 0;
        __syncthreads();
        if (t < 256) cur[t] += u;
        __syncthreads();
    }
    if (t < 256) {
        int node = (b << 8) + t;
        int base = bbase[b] + cur[t] - h;
        if (node < NN) row_ptr[node] = base;
        cur[t] = base;
    }
    __syncthreads();
    int total = min(scnt, SEMAX);
    for (int i = t; i < total; i += 512) {
        unsigned int v = sE[i];
        int pos = atomicAdd(&cur[v & 255u], 1);
        srcs[pos] = (int)(v >> 16);
    }
}

// ---------------------------------------------------------------------------
// Mean aggregation, hi-plane in -> hi-plane out. One wave per node (max TLP
// for the latency-bound gather — R15 fusion proved this is the key resource),
// 8-deep load ILP.
__global__ void k_agg(const unsigned int* __restrict__ inh, const int* __restrict__ row_ptr,
                      const int* __restrict__ srcs, unsigned int* __restrict__ oh) {
    int node = blockIdx.x * 4 + (threadIdx.x >> 6);
    if (node >= NN) return;
    int lane = threadIdx.x & 63;
    int b = row_ptr[node], e = row_ptr[node + 1];
    float a0 = 0.f, a1 = 0.f;
    int i = b;
    for (; i + 7 < e; i += 8) {
        unsigned int p0 = inh[(size_t)srcs[i + 0] * 64 + lane];
        unsigned int p1 = inh[(size_t)srcs[i + 1] * 64 + lane];
        unsigned int p2 = inh[(size_t)srcs[i + 2] * 64 + lane];
        unsigned int p3 = inh[(size_t)srcs[i + 3] * 64 + lane];
        unsigned int p4 = inh[(size_t)srcs[i + 4] * 64 + lane];
        unsigned int p5 = inh[(size_t)srcs[i + 5] * 64 + lane];
        unsigned int p6 = inh[(size_t)srcs[i + 6] * 64 + lane];
        unsigned int p7 = inh[(size_t)srcs[i + 7] * 64 + lane];
        float u0, u1;
        unpack2h(p0, u0, u1); a0 += u0; a1 += u1;
        unpack2h(p1, u0, u1); a0 += u0; a1 += u1;
        unpack2h(p2, u0, u1); a0 += u0; a1 += u1;
        unpack2h(p3, u0, u1); a0 += u0; a1 += u1;
        unpack2h(p4, u0, u1); a0 += u0; a1 += u1;
        unpack2h(p5, u0, u1); a0 += u0; a1 += u1;
        unpack2h(p6, u0, u1); a0 += u0; a1 += u1;
        unpack2h(p7, u0, u1); a0 += u0; a1 += u1;
    }
    for (; i < e; ++i) {
        unsigned int p = inh[(size_t)srcs[i] * 64 + lane];
        float u0, u1;
        unpack2h(p, u0, u1); a0 += u0; a1 += u1;
    }
    int deg = e - b;
    float inv = 1.0f / (float)(deg > 0 ? deg : 1);
    oh[(size_t)node * 64 + lane] = pack2h((_Float16)(a0 * inv), (_Float16)(a1 * inv));
}

// ---------------------------------------------------------------------------
// f16 MFMA GEMM, B staged in LDS in fragment layout (hi+lo planes).
// A: single hi plane (agg for k<128, self for k>=128); per (ks,n):
//   acc += Ah*Bh + Ah*Bl
template <int NT, int KPS, bool PACKOUT>
__launch_bounds__(256, 4)
__global__ void k_mfma(const unsigned short* __restrict__ A1h,
                       const unsigned short* __restrict__ A2h,
                       const unsigned short* __restrict__ Bthf, const unsigned short* __restrict__ Btlf,
                       const float* __restrict__ bias, float* __restrict__ outf,
                       unsigned short* __restrict__ outh, const int NC) {
    constexpr int STAGE_ELEMS = KPS * NT * 64 * 8;
    constexpr int STAGE_U4 = STAGE_ELEMS / 8;
    __shared__ unsigned short sBh[STAGE_ELEMS];
    __shared__ unsigned short sBl[STAGE_ELEMS];

    const int tid = threadIdx.x;
    const int wave = tid >> 6, lane = tid & 63;
    const int quad = lane >> 4, mr = lane & 15;
    const int m0 = blockIdx.x * 64 + wave * 16;
    const int row = m0 + mr;
    const bool rok = row < NN;

    f32x4 acc[NT] = {};
    const f16x8 zero = {};

    auto aload = [&](int ks) -> f16x8 {
        const int ko = ((ks * 32) & 127) + quad * 8;
        const unsigned short* base = (ks < 4) ? A1h : A2h;
        return rok ? *(const f16x8*)(base + (size_t)row * 128 + ko) : zero;
    };

    f16x8 cah = aload(0), pah;

#pragma unroll
    for (int s = 0; s < 8 / KPS; ++s) {
        const uint4* gh = (const uint4*)(Bthf + (size_t)s * STAGE_ELEMS);
        const uint4* gl = (const uint4*)(Btlf + (size_t)s * STAGE_ELEMS);
        uint4* lh = (uint4*)sBh;
        uint4* ll = (uint4*)sBl;
        if (s) __syncthreads();
        for (int i = tid; i < STAGE_U4; i += 256) {
            lh[i] = gh[i];
            ll[i] = gl[i];
        }
        __syncthreads();

#pragma unroll
        for (int kl = 0; kl < KPS; ++kl) {
            const int ks = s * KPS + kl;
            if (ks < 7) pah = aload(ks + 1);
#pragma unroll
            for (int n = 0; n < NT; ++n) {
                const int fo = ((kl * NT + n) * 64 + lane) * 8;
                f16x8 bh = *(const f16x8*)(sBh + fo);
                f16x8 bl = *(const f16x8*)(sBl + fo);
                acc[n] = __builtin_amdgcn_mfma_f32_16x16x32_f16(cah, bh, acc[n], 0, 0, 0);
                acc[n] = __builtin_amdgcn_mfma_f32_16x16x32_f16(cah, bl, acc[n], 0, 0, 0);
            }
            cah = pah;
        }
    }

    // Epilogue. C/D layout: col = lane&15, row = quad*4 + reg.
#pragma unroll
    for (int n = 0; n < NT; ++n) {
        int col = n * 16 + mr;
        float bv = (col < NC) ? bias[col] : 0.f;
#pragma unroll
        for (int r = 0; r < 4; ++r) {
            int orow = m0 + quad * 4 + r;
            if (orow < NN && col < NC) {
                float v = acc[n][r] + bv;
                v = v > 0.f ? v : 0.f;
                if (PACKOUT) {
                    union { _Float16 f; unsigned short u; } ch;
                    ch.f = (_Float16)v;
                    outh[(size_t)orow * 128 + col] = ch.u;
                } else {
                    outf[(size_t)orow * NC + col] = v;
                }
            }
        }
    }
}

// ---------------------------------------------------------------------------
extern "C" void kernel_launch(void* const* d_in, const int* in_sizes, int n_in,
                              void* d_out, int out_size, void* d_ws, size_t ws_size,
                              hipStream_t stream) {
    const float* x    = (const float*)d_in[0];
    const int*   ei   = (const int*)d_in[1];
    const float* w1_l = (const float*)d_in[2];
    const float* w1_r = (const float*)d_in[3];
    const float* b1   = (const float*)d_in[4];
    const float* w2_l = (const float*)d_in[5];
    const float* w2_r = (const float*)d_in[6];
    const float* b2   = (const float*)d_in[7];
    const float* w3_l = (const float*)d_in[8];
    const float* w3_r = (const float*)d_in[9];
    const float* b3   = (const float*)d_in[10];
    float* out = (float*)d_out;

    char* w = (char*)d_ws;
    size_t off = 0;
    auto alloc = [&](size_t bytes) -> void* {
        void* p = w + off;
        off += (bytes + 255) / 256 * 256;
        return p;
    };
    int* row_ptr = (int*)alloc((size_t)(NN + 1) * 4);
    int* srcs    = (int*)alloc((size_t)NE * 4);
    int* cellcnt = (int*)alloc((size_t)NBK * PB * 4);
    int* celloff = (int*)alloc((size_t)NBK * PB * 4);
    int* bsum    = (int*)alloc((size_t)NBK * 4);
    int* bbase   = (int*)alloc((size_t)(NBK + 1) * 4);
    unsigned int* pairs = (unsigned int*)alloc((size_t)PB * EPB * 4);
    unsigned short* xh   = (unsigned short*)alloc((size_t)NN * DD * 2);  // also h2h
    unsigned short* aggh = (unsigned short*)alloc((size_t)NN * DD * 2);
    unsigned short* h1h  = (unsigned short*)alloc((size_t)NN * DD * 2);
    unsigned short* bt1h = (unsigned short*)alloc((size_t)8 * 8 * 64 * 8 * 2);
    unsigned short* bt1l = (unsigned short*)alloc((size_t)8 * 8 * 64 * 8 * 2);
    unsigned short* bt2h = (unsigned short*)alloc((size_t)8 * 8 * 64 * 8 * 2);
    unsigned short* bt2l = (unsigned short*)alloc((size_t)8 * 8 * 64 * 8 * 2);
    unsigned short* bt3h = (unsigned short*)alloc((size_t)8 * 3 * 64 * 8 * 2);
    unsigned short* bt3l = (unsigned short*)alloc((size_t)8 * 3 * 64 * 8 * 2);
    unsigned short* h2h = xh;  // x dead after layer-1 GEMM
    (void)ws_size;

    k_front<<<PB + CVB + WB, 256, 0, stream>>>(ei, cellcnt, celloff, pairs, x, xh,
                                               w1_l, w1_r, w2_l, w2_r, w3_l, w3_r,
                                               bt1h, bt1l, bt2h, bt2l, bt3h, bt3l);
    k_scan_ba<<<NBK, 256, 0, stream>>>(cellcnt, bsum);
    k_scan_bb<<<1, 256, 0, stream>>>(bsum, bbase, row_ptr);
    k_fill2<<<NBK, 512, 0, stream>>>(pairs, cellcnt, celloff, bbase, row_ptr, srcs);

    const int gmb = (NN + 63) / 64;   // 782 (GEMM m-blocks)
    const int gab = (NN + 3) / 4;     // 12500 (agg blocks, 4 nodes each)
    // Layer 1
    k_agg<<<gab, 256, 0, stream>>>((const unsigned int*)xh, row_ptr, srcs,
                                   (unsigned int*)aggh);
    k_mfma<8, 2, true><<<gmb, 256, 0, stream>>>(aggh, xh, bt1h, bt1l, b1,
                                                nullptr, h1h, DD);
    // Layer 2 (h2h aliases xh; x is dead)
    k_agg<<<gab, 256, 0, stream>>>((const unsigned int*)h1h, row_ptr, srcs,
                                   (unsigned int*)aggh);
    k_mfma<8, 2, true><<<gmb, 256, 0, stream>>>(aggh, h1h, bt2h, bt2l, b2,
                                                nullptr, h2h, DD);
    // Layer 3
    k_agg<<<gab, 256, 0, stream>>>((const unsigned int*)h2h, row_ptr, srcs,
                                   (unsigned int*)aggh);
    k_mfma<3, 2, false><<<gmb, 256, 0, stream>>>(aggh, h2h, bt3h, bt3l, b3,
                                                 out, nullptr, NCLS);
}

// Round 17
// 252.462 us; speedup vs baseline: 1.7611x; 1.0969x over previous
//
#include <hip/hip_runtime.h>
#include <hip/hip_bf16.h>

#define NN 50000
#define NE 800000
#define DD 128
#define NCLS 40
#define NBK ((NN + 255) >> 8)      // 196 dst-buckets of 256 nodes
#define EPB 1024                   // edges per k_part block (4/thread)
#define PB ((NE + EPB - 1) / EPB)  // 782 partition blocks
#define CVB ((NN * DD / 4) / 256)  // 6250 cvt blocks
#define WB 384                     // weight-convert blocks (192 units x 2 halves)
#define SEMAX 5120                 // max edges per bucket (mean 4081, sd 64)

typedef _Float16 f16x8 __attribute__((ext_vector_type(8)));  // 8 f16 (4 VGPRs)
typedef _Float16 f16x4 __attribute__((ext_vector_type(4)));
typedef float f32x4 __attribute__((ext_vector_type(4)));     // MFMA acc

__device__ __forceinline__ unsigned int pack2h(_Float16 a, _Float16 b) {
    union { _Float16 h[2]; unsigned int u; } c;
    c.h[0] = a; c.h[1] = b;
    return c.u;
}
__device__ __forceinline__ void unpack2h(unsigned int p, float& a, float& b) {
    union { unsigned int u; _Float16 h[2]; } c;
    c.u = p;
    a = (float)c.h[0]; b = (float)c.h[1];
}

// ---------------------------------------------------------------------------
// Mega front kernel.
//   Blocks [0,PB):            LDS bucket-sort of 1024 edges -> dense chunk
//   Blocks [PB,PB+CVB):       x fp32 -> f16 hi plane
//   Blocks [PB+CVB,+WB):      all 3 layers' B -> MFMA-fragment-major hi/lo
__global__ void k_front(const int* __restrict__ ei, int* __restrict__ cellcnt,
                        int* __restrict__ celloff, unsigned int* __restrict__ pairs,
                        const float* __restrict__ x, unsigned short* __restrict__ xh,
                        const float* __restrict__ w1l, const float* __restrict__ w1r,
                        const float* __restrict__ w2l, const float* __restrict__ w2r,
                        const float* __restrict__ w3l, const float* __restrict__ w3r,
                        unsigned short* __restrict__ bt1h, unsigned short* __restrict__ bt1l,
                        unsigned short* __restrict__ bt2h, unsigned short* __restrict__ bt2l,
                        unsigned short* __restrict__ bt3h, unsigned short* __restrict__ bt3l) {
    if (blockIdx.x >= PB + CVB) {
        // ---- weight conversion ----
        int idx = blockIdx.x - (PB + CVB);
        int w = idx >> 1, half = idx & 1;
        int ks = w & 7, tmp = w >> 3;
        int nt = tmp & 7, layer = tmp >> 3;
        const int NT = (layer == 2) ? 3 : 8;
        const int NC = (layer == 2) ? NCLS : DD;
        if (nt >= NT) return;
        const float* wl = (layer == 0) ? w1l : (layer == 1) ? w2l : w3l;
        const float* wr = (layer == 0) ? w1r : (layer == 1) ? w2r : w3r;
        unsigned short* bh = (layer == 0) ? bt1h : (layer == 1) ? bt2h : bt3h;
        unsigned short* bl = (layer == 0) ? bt1l : (layer == 1) ? bt2l : bt3l;
        int t = threadIdx.x;
        int j = t & 7, lane = (t >> 3) + half * 32;
        int row = nt * 16 + (lane & 15);          // output column n
        int k = ks * 32 + (lane >> 4) * 8 + j;    // K position in [Wl;Wr]
        float v = 0.f;
        if (row < NC)
            v = (k < 128) ? wl[(size_t)k * NC + row] : wr[(size_t)(k - 128) * NC + row];
        _Float16 h = (_Float16)v;
        _Float16 l = (_Float16)(v - (float)h);
        size_t o = ((size_t)(ks * NT + nt) * 64 + lane) * 8 + j;
        union { _Float16 f; unsigned short u; } ch, cl;
        ch.f = h; cl.f = l;
        bh[o] = ch.u;
        bl[o] = cl.u;
        return;
    }
    if (blockIdx.x >= PB) {
        // ---- x conversion ----
        int i = (blockIdx.x - PB) * 256 + threadIdx.x;
        float4 v = ((const float4*)x)[i];
        f16x4 h;
        h[0] = (_Float16)v.x; h[1] = (_Float16)v.y;
        h[2] = (_Float16)v.z; h[3] = (_Float16)v.w;
        *(f16x4*)(xh + (size_t)i * 4) = h;
        return;
    }
    // ---- edge partition: LDS bucket-sort, dense chunk out ----
    __shared__ int hist[NBK];
    __shared__ int s[256];
    __shared__ unsigned int sE[EPB];
    __shared__ int nz;
    const int t = threadIdx.x, blk = blockIdx.x;
    const int e0 = blk * EPB;
    if (t == 0) nz = 0;
    for (int i = t; i < NBK; i += 256) hist[i] = 0;
    __syncthreads();
    int any = 0;
    for (int i = t; i < EPB; i += 256)
        if (ei[2 * e0 + 2 * i + 1] != 0) any = 1;
    if (any) atomicOr(&nz, 1);
    __syncthreads();
    const int is64 = (nz == 0);
    unsigned int v[EPB / 256];
    int eb[EPB / 256], er[EPB / 256];
#pragma unroll
    for (int j = 0; j < EPB / 256; ++j) {
        int e = e0 + j * 256 + t;
        if (e < NE) {
            int sv, d;
            if (is64) { sv = ei[2 * e]; d = ei[2 * (NE + e)]; }
            else      { sv = ei[e];     d = ei[NE + e]; }
            v[j] = ((unsigned)sv << 16) | (unsigned)d;
            eb[j] = d >> 8;
            er[j] = atomicAdd(&hist[eb[j]], 1);
        } else {
            eb[j] = -1;
        }
    }
    __syncthreads();
    int hv = (t < NBK) ? hist[t] : 0;
    s[t] = hv;
    __syncthreads();
#pragma unroll
    for (int off = 1; off < 256; off <<= 1) {
        int u = (t >= off) ? s[t - off] : 0;
        __syncthreads();
        s[t] += u;
        __syncthreads();
    }
#pragma unroll
    for (int j = 0; j < EPB / 256; ++j)
        if (eb[j] >= 0) sE[s[eb[j]] - hist[eb[j]] + er[j]] = v[j];
    __syncthreads();
    ((uint4*)(pairs + (size_t)blk * EPB))[t] = ((const uint4*)sE)[t];
    for (int i = t; i < NBK; i += 256) {
        cellcnt[(size_t)i * PB + blk] = hist[i];
        celloff[(size_t)i * PB + blk] = s[i] - hist[i];
    }
}

// Bucket totals: 196 blocks, block b reduces its (coalesced) cellcnt row.
__global__ void k_scan_ba(const int* __restrict__ cellcnt, int* __restrict__ bsum) {
    __shared__ int red[256];
    int b = blockIdx.x, t = threadIdx.x;
    int acc = 0;
    for (int i = t; i < PB; i += 256) acc += cellcnt[(size_t)b * PB + i];
    red[t] = acc;
    __syncthreads();
#pragma unroll
    for (int off = 128; off > 0; off >>= 1) {
        if (t < off) red[t] += red[t + off];
        __syncthreads();
    }
    if (t == 0) bsum[b] = red[0];
}

// Phase 2 (+ folded bucket-base scan): one 512-thread block per bucket.
// Redundantly prefix-sums the 196 bucket totals in LDS to get this bucket's
// base; then per-node histogram + prefix -> row_ptr; then LDS-cursor scatter
// into the bucket's contiguous srcs run.
__global__ void k_fill2(const unsigned int* __restrict__ pairs,
                        const int* __restrict__ cellcnt,
                        const int* __restrict__ celloff,
                        const int* __restrict__ bsum,
                        int* __restrict__ row_ptr, int* __restrict__ srcs) {
    __shared__ unsigned int sE[SEMAX];
    __shared__ int hist[256];
    __shared__ int cur[256];
    __shared__ int sb[256];
    __shared__ int scnt;
    const int b = blockIdx.x, t = threadIdx.x;
    // ---- folded scan_bb: exclusive prefix of bsum in LDS
    if (t < 256) {
        int v = (t < NBK) ? bsum[t] : 0;
        sb[t] = v;
    }
    if (t == 0) scnt = 0;
    if (t < 256) hist[t] = 0;
    __syncthreads();
#pragma unroll
    for (int off = 1; off < 256; off <<= 1) {
        int u = (t >= off && t < 256) ? sb[t - off] : 0;
        __syncthreads();
        if (t < 256) sb[t] += u;
        __syncthreads();
    }
    const int bbase = (b == 0) ? 0 : sb[b - 1];
    if (b == NBK - 1 && t == 0) row_ptr[NN] = sb[NBK - 1];
    // ---- compact this bucket's runs into LDS
    for (int blk = t; blk < PB; blk += 512) {
        int cnt = cellcnt[(size_t)b * PB + blk];
        if (cnt) {
            int off = celloff[(size_t)b * PB + blk];
            int base = atomicAdd(&scnt, cnt);
            if (base + cnt <= SEMAX) {
                const unsigned int* pp = pairs + (size_t)blk * EPB + off;
                for (int j = 0; j < cnt; ++j) {
                    unsigned int v = pp[j];
                    sE[base + j] = v;
                    atomicAdd(&hist[v & 255u], 1);
                }
            }
        }
    }
    __syncthreads();
    int h = (t < 256) ? hist[t] : 0;
    if (t < 256) cur[t] = h;
    __syncthreads();
#pragma unroll
    for (int off = 1; off < 256; off <<= 1) {
        int u = (t >= off && t < 256) ? cur[t - off] : 0;
        __syncthreads();
        if (t < 256) cur[t] += u;
        __syncthreads();
    }
    if (t < 256) {
        int node = (b << 8) + t;
        int base = bbase + cur[t] - h;
        if (node < NN) row_ptr[node] = base;
        cur[t] = base;
    }
    __syncthreads();
    int total = min(scnt, SEMAX);
    for (int i = t; i < total; i += 512) {
        unsigned int v = sE[i];
        int pos = atomicAdd(&cur[v & 255u], 1);
        srcs[pos] = (int)(v >> 16);
    }
}

// ---------------------------------------------------------------------------
// Mean aggregation, hi-plane in -> hi-plane out. One wave per node (max TLP
// — R15 fusion proved this is the key resource), 8-deep load ILP with a
// masked 8-wide tail (no serial remainder latency).
__global__ void k_agg(const unsigned int* __restrict__ inh, const int* __restrict__ row_ptr,
                      const int* __restrict__ srcs, unsigned int* __restrict__ oh) {
    int node = blockIdx.x * 4 + (threadIdx.x >> 6);
    if (node >= NN) return;
    int lane = threadIdx.x & 63;
    int b = row_ptr[node], e = row_ptr[node + 1];
    float a0 = 0.f, a1 = 0.f;
    int nfull = (e - b) & ~7;
    int i = b;
    for (; i < b + nfull; i += 8) {
        unsigned int p0 = inh[(size_t)srcs[i + 0] * 64 + lane];
        unsigned int p1 = inh[(size_t)srcs[i + 1] * 64 + lane];
        unsigned int p2 = inh[(size_t)srcs[i + 2] * 64 + lane];
        unsigned int p3 = inh[(size_t)srcs[i + 3] * 64 + lane];
        unsigned int p4 = inh[(size_t)srcs[i + 4] * 64 + lane];
        unsigned int p5 = inh[(size_t)srcs[i + 5] * 64 + lane];
        unsigned int p6 = inh[(size_t)srcs[i + 6] * 64 + lane];
        unsigned int p7 = inh[(size_t)srcs[i + 7] * 64 + lane];
        float u0, u1;
        unpack2h(p0, u0, u1); a0 += u0; a1 += u1;
        unpack2h(p1, u0, u1); a0 += u0; a1 += u1;
        unpack2h(p2, u0, u1); a0 += u0; a1 += u1;
        unpack2h(p3, u0, u1); a0 += u0; a1 += u1;
        unpack2h(p4, u0, u1); a0 += u0; a1 += u1;
        unpack2h(p5, u0, u1); a0 += u0; a1 += u1;
        unpack2h(p6, u0, u1); a0 += u0; a1 += u1;
        unpack2h(p7, u0, u1); a0 += u0; a1 += u1;
    }
    int rem = e - i;
    if (rem > 0) {
        unsigned int p[8];
#pragma unroll
        for (int j = 0; j < 8; ++j) {
            int idx = i + j;
            if (idx > e - 1) idx = e - 1;  // clamped (predicated-out below)
            p[j] = inh[(size_t)srcs[idx] * 64 + lane];
        }
#pragma unroll
        for (int j = 0; j < 8; ++j) {
            float u0, u1;
            unpack2h(p[j], u0, u1);
            if (j < rem) { a0 += u0; a1 += u1; }
        }
    }
    int deg = e - b;
    float inv = 1.0f / (float)(deg > 0 ? deg : 1);
    oh[(size_t)node * 64 + lane] = pack2h((_Float16)(a0 * inv), (_Float16)(a1 * inv));
}

// ---------------------------------------------------------------------------
// f16 MFMA GEMM, B staged in LDS in fragment layout (hi+lo planes).
// A: single hi plane (agg for k<128, self for k>=128); per (ks,n):
//   acc += Ah*Bh + Ah*Bl
template <int NT, int KPS, bool PACKOUT>
__launch_bounds__(256, 4)
__global__ void k_mfma(const unsigned short* __restrict__ A1h,
                       const unsigned short* __restrict__ A2h,
                       const unsigned short* __restrict__ Bthf, const unsigned short* __restrict__ Btlf,
                       const float* __restrict__ bias, float* __restrict__ outf,
                       unsigned short* __restrict__ outh, const int NC) {
    constexpr int STAGE_ELEMS = KPS * NT * 64 * 8;
    constexpr int STAGE_U4 = STAGE_ELEMS / 8;
    __shared__ unsigned short sBh[STAGE_ELEMS];
    __shared__ unsigned short sBl[STAGE_ELEMS];

    const int tid = threadIdx.x;
    const int wave = tid >> 6, lane = tid & 63;
    const int quad = lane >> 4, mr = lane & 15;
    const int m0 = blockIdx.x * 64 + wave * 16;
    const int row = m0 + mr;
    const bool rok = row < NN;

    f32x4 acc[NT] = {};
    const f16x8 zero = {};

    auto aload = [&](int ks) -> f16x8 {
        const int ko = ((ks * 32) & 127) + quad * 8;
        const unsigned short* base = (ks < 4) ? A1h : A2h;
        return rok ? *(const f16x8*)(base + (size_t)row * 128 + ko) : zero;
    };

    f16x8 cah = aload(0), pah;

#pragma unroll
    for (int s = 0; s < 8 / KPS; ++s) {
        const uint4* gh = (const uint4*)(Bthf + (size_t)s * STAGE_ELEMS);
        const uint4* gl = (const uint4*)(Btlf + (size_t)s * STAGE_ELEMS);
        uint4* lh = (uint4*)sBh;
        uint4* ll = (uint4*)sBl;
        if (s) __syncthreads();
        for (int i = tid; i < STAGE_U4; i += 256) {
            lh[i] = gh[i];
            ll[i] = gl[i];
        }
        __syncthreads();

#pragma unroll
        for (int kl = 0; kl < KPS; ++kl) {
            const int ks = s * KPS + kl;
            if (ks < 7) pah = aload(ks + 1);
#pragma unroll
            for (int n = 0; n < NT; ++n) {
                const int fo = ((kl * NT + n) * 64 + lane) * 8;
                f16x8 bh = *(const f16x8*)(sBh + fo);
                f16x8 bl = *(const f16x8*)(sBl + fo);
                acc[n] = __builtin_amdgcn_mfma_f32_16x16x32_f16(cah, bh, acc[n], 0, 0, 0);
                acc[n] = __builtin_amdgcn_mfma_f32_16x16x32_f16(cah, bl, acc[n], 0, 0, 0);
            }
            cah = pah;
        }
    }

    // Epilogue. C/D layout: col = lane&15, row = quad*4 + reg.
#pragma unroll
    for (int n = 0; n < NT; ++n) {
        int col = n * 16 + mr;
        float bv = (col < NC) ? bias[col] : 0.f;
#pragma unroll
        for (int r = 0; r < 4; ++r) {
            int orow = m0 + quad * 4 + r;
            if (orow < NN && col < NC) {
                float v = acc[n][r] + bv;
                v = v > 0.f ? v : 0.f;
                if (PACKOUT) {
                    union { _Float16 f; unsigned short u; } ch;
                    ch.f = (_Float16)v;
                    outh[(size_t)orow * 128 + col] = ch.u;
                } else {
                    outf[(size_t)orow * NC + col] = v;
                }
            }
        }
    }
}

// ---------------------------------------------------------------------------
extern "C" void kernel_launch(void* const* d_in, const int* in_sizes, int n_in,
                              void* d_out, int out_size, void* d_ws, size_t ws_size,
                              hipStream_t stream) {
    const float* x    = (const float*)d_in[0];
    const int*   ei   = (const int*)d_in[1];
    const float* w1_l = (const float*)d_in[2];
    const float* w1_r = (const float*)d_in[3];
    const float* b1   = (const float*)d_in[4];
    const float* w2_l = (const float*)d_in[5];
    const float* w2_r = (const float*)d_in[6];
    const float* b2   = (const float*)d_in[7];
    const float* w3_l = (const float*)d_in[8];
    const float* w3_r = (const float*)d_in[9];
    const float* b3   = (const float*)d_in[10];
    float* out = (float*)d_out;

    char* w = (char*)d_ws;
    size_t off = 0;
    auto alloc = [&](size_t bytes) -> void* {
        void* p = w + off;
        off += (bytes + 255) / 256 * 256;
        return p;
    };
    int* row_ptr = (int*)alloc((size_t)(NN + 1) * 4);
    int* srcs    = (int*)alloc((size_t)NE * 4);
    int* cellcnt = (int*)alloc((size_t)NBK * PB * 4);
    int* celloff = (int*)alloc((size_t)NBK * PB * 4);
    int* bsum    = (int*)alloc((size_t)NBK * 4);
    unsigned int* pairs = (unsigned int*)alloc((size_t)PB * EPB * 4);
    unsigned short* xh   = (unsigned short*)alloc((size_t)NN * DD * 2);  // also h2h
    unsigned short* aggh = (unsigned short*)alloc((size_t)NN * DD * 2);
    unsigned short* h1h  = (unsigned short*)alloc((size_t)NN * DD * 2);
    unsigned short* bt1h = (unsigned short*)alloc((size_t)8 * 8 * 64 * 8 * 2);
    unsigned short* bt1l = (unsigned short*)alloc((size_t)8 * 8 * 64 * 8 * 2);
    unsigned short* bt2h = (unsigned short*)alloc((size_t)8 * 8 * 64 * 8 * 2);
    unsigned short* bt2l = (unsigned short*)alloc((size_t)8 * 8 * 64 * 8 * 2);
    unsigned short* bt3h = (unsigned short*)alloc((size_t)8 * 3 * 64 * 8 * 2);
    unsigned short* bt3l = (unsigned short*)alloc((size_t)8 * 3 * 64 * 8 * 2);
    unsigned short* h2h = xh;  // x dead after layer-1 GEMM
    (void)ws_size;

    k_front<<<PB + CVB + WB, 256, 0, stream>>>(ei, cellcnt, celloff, pairs, x, xh,
                                               w1_l, w1_r, w2_l, w2_r, w3_l, w3_r,
                                               bt1h, bt1l, bt2h, bt2l, bt3h, bt3l);
    k_scan_ba<<<NBK, 256, 0, stream>>>(cellcnt, bsum);
    k_fill2<<<NBK, 512, 0, stream>>>(pairs, cellcnt, celloff, bsum, row_ptr, srcs);

    const int gmb = (NN + 63) / 64;   // 782 (GEMM m-blocks)
    const int gab = (NN + 3) / 4;     // 12500 (agg blocks, 4 nodes each)
    // Layer 1
    k_agg<<<gab, 256, 0, stream>>>((const unsigned int*)xh, row_ptr, srcs,
                                   (unsigned int*)aggh);
    k_mfma<8, 2, true><<<gmb, 256, 0, stream>>>(aggh, xh, bt1h, bt1l, b1,
                                                nullptr, h1h, DD);
    // Layer 2 (h2h aliases xh; x is dead)
    k_agg<<<gab, 256, 0, stream>>>((const unsigned int*)h1h, row_ptr, srcs,
                                   (unsigned int*)aggh);
    k_mfma<8, 2, true><<<gmb, 256, 0, stream>>>(aggh, h1h, bt2h, bt2l, b2,
                                                nullptr, h2h, DD);
    // Layer 3
    k_agg<<<gab, 256, 0, stream>>>((const unsigned int*)h2h, row_ptr, srcs,
                                   (unsigned int*)aggh);
    k_mfma<3, 2, false><<<gmb, 256, 0, stream>>>(aggh, h2h, bt3h, bt3l, b3,
                                                 out, nullptr, NCLS);
}

// Round 18
// 241.166 us; speedup vs baseline: 1.8436x; 1.0468x over previous
//
#include <hip/hip_runtime.h>
#include <hip/hip_bf16.h>

#define NN 50000
#define NE 800000
#define DD 128
#define NCLS 40
#define NBK ((NN + 255) >> 8)      // 196 dst-buckets of 256 nodes
#define EPB 1024                   // edges per k_part block (4/thread)
#define PB ((NE + EPB - 1) / EPB)  // 782 partition blocks
#define CVB ((NN * DD / 4) / 256)  // 6250 cvt blocks
#define WB 384                     // weight-convert blocks (192 units x 2 halves)
#define SEMAX 5120                 // max edges per bucket (mean 4081, sd 64)

typedef _Float16 f16x8 __attribute__((ext_vector_type(8)));  // 8 f16 (4 VGPRs)
typedef _Float16 f16x4 __attribute__((ext_vector_type(4)));
typedef float f32x4 __attribute__((ext_vector_type(4)));     // MFMA acc

__device__ __forceinline__ unsigned int pack2h(_Float16 a, _Float16 b) {
    union { _Float16 h[2]; unsigned int u; } c;
    c.h[0] = a; c.h[1] = b;
    return c.u;
}
__device__ __forceinline__ void unpack2h(unsigned int p, float& a, float& b) {
    union { unsigned int u; _Float16 h[2]; } c;
    c.u = p;
    a = (float)c.h[0]; b = (float)c.h[1];
}

// ---------------------------------------------------------------------------
// Mega front kernel.
//   Blocks [0,PB):            LDS bucket-sort of 1024 edges -> dense chunk
//   Blocks [PB,PB+CVB):       x fp32 -> f16 hi plane
//   Blocks [PB+CVB,+WB):      all 3 layers' B -> MFMA-fragment-major f16
__global__ void k_front(const int* __restrict__ ei, int* __restrict__ cellcnt,
                        int* __restrict__ celloff, unsigned int* __restrict__ pairs,
                        const float* __restrict__ x, unsigned short* __restrict__ xh,
                        const float* __restrict__ w1l, const float* __restrict__ w1r,
                        const float* __restrict__ w2l, const float* __restrict__ w2r,
                        const float* __restrict__ w3l, const float* __restrict__ w3r,
                        unsigned short* __restrict__ bt1h,
                        unsigned short* __restrict__ bt2h,
                        unsigned short* __restrict__ bt3h) {
    if (blockIdx.x >= PB + CVB) {
        // ---- weight conversion (f16 hi only; error budget covers it) ----
        int idx = blockIdx.x - (PB + CVB);
        int w = idx >> 1, half = idx & 1;
        int ks = w & 7, tmp = w >> 3;
        int nt = tmp & 7, layer = tmp >> 3;
        const int NT = (layer == 2) ? 3 : 8;
        const int NC = (layer == 2) ? NCLS : DD;
        if (nt >= NT) return;
        const float* wl = (layer == 0) ? w1l : (layer == 1) ? w2l : w3l;
        const float* wr = (layer == 0) ? w1r : (layer == 1) ? w2r : w3r;
        unsigned short* bh = (layer == 0) ? bt1h : (layer == 1) ? bt2h : bt3h;
        int t = threadIdx.x;
        int j = t & 7, lane = (t >> 3) + half * 32;
        int row = nt * 16 + (lane & 15);          // output column n
        int k = ks * 32 + (lane >> 4) * 8 + j;    // K position in [Wl;Wr]
        float v = 0.f;
        if (row < NC)
            v = (k < 128) ? wl[(size_t)k * NC + row] : wr[(size_t)(k - 128) * NC + row];
        union { _Float16 f; unsigned short u; } ch;
        ch.f = (_Float16)v;
        bh[((size_t)(ks * NT + nt) * 64 + lane) * 8 + j] = ch.u;
        return;
    }
    if (blockIdx.x >= PB) {
        // ---- x conversion ----
        int i = (blockIdx.x - PB) * 256 + threadIdx.x;
        float4 v = ((const float4*)x)[i];
        f16x4 h;
        h[0] = (_Float16)v.x; h[1] = (_Float16)v.y;
        h[2] = (_Float16)v.z; h[3] = (_Float16)v.w;
        *(f16x4*)(xh + (size_t)i * 4) = h;
        return;
    }
    // ---- edge partition: LDS bucket-sort, dense chunk out ----
    __shared__ int hist[NBK];
    __shared__ int s[256];
    __shared__ unsigned int sE[EPB];
    __shared__ int nz;
    const int t = threadIdx.x, blk = blockIdx.x;
    const int e0 = blk * EPB;
    if (t == 0) nz = 0;
    for (int i = t; i < NBK; i += 256) hist[i] = 0;
    __syncthreads();
    int any = 0;
    for (int i = t; i < EPB; i += 256)
        if (ei[2 * e0 + 2 * i + 1] != 0) any = 1;
    if (any) atomicOr(&nz, 1);
    __syncthreads();
    const int is64 = (nz == 0);
    unsigned int v[EPB / 256];
    int eb[EPB / 256], er[EPB / 256];
#pragma unroll
    for (int j = 0; j < EPB / 256; ++j) {
        int e = e0 + j * 256 + t;
        if (e < NE) {
            int sv, d;
            if (is64) { sv = ei[2 * e]; d = ei[2 * (NE + e)]; }
            else      { sv = ei[e];     d = ei[NE + e]; }
            v[j] = ((unsigned)sv << 16) | (unsigned)d;
            eb[j] = d >> 8;
            er[j] = atomicAdd(&hist[eb[j]], 1);
        } else {
            eb[j] = -1;
        }
    }
    __syncthreads();
    int hv = (t < NBK) ? hist[t] : 0;
    s[t] = hv;
    __syncthreads();
#pragma unroll
    for (int off = 1; off < 256; off <<= 1) {
        int u = (t >= off) ? s[t - off] : 0;
        __syncthreads();
        s[t] += u;
        __syncthreads();
    }
#pragma unroll
    for (int j = 0; j < EPB / 256; ++j)
        if (eb[j] >= 0) sE[s[eb[j]] - hist[eb[j]] + er[j]] = v[j];
    __syncthreads();
    ((uint4*)(pairs + (size_t)blk * EPB))[t] = ((const uint4*)sE)[t];
    for (int i = t; i < NBK; i += 256) {
        cellcnt[(size_t)i * PB + blk] = hist[i];
        celloff[(size_t)i * PB + blk] = s[i] - hist[i];
    }
}

// Bucket totals: 196 blocks, block b reduces its (coalesced) cellcnt row.
__global__ void k_scan_ba(const int* __restrict__ cellcnt, int* __restrict__ bsum) {
    __shared__ int red[256];
    int b = blockIdx.x, t = threadIdx.x;
    int acc = 0;
    for (int i = t; i < PB; i += 256) acc += cellcnt[(size_t)b * PB + i];
    red[t] = acc;
    __syncthreads();
#pragma unroll
    for (int off = 128; off > 0; off >>= 1) {
        if (t < off) red[t] += red[t + off];
        __syncthreads();
    }
    if (t == 0) bsum[b] = red[0];
}

// Phase 2 (+ folded bucket-base scan): one 512-thread block per bucket.
__global__ void k_fill2(const unsigned int* __restrict__ pairs,
                        const int* __restrict__ cellcnt,
                        const int* __restrict__ celloff,
                        const int* __restrict__ bsum,
                        int* __restrict__ row_ptr, int* __restrict__ srcs) {
    __shared__ unsigned int sE[SEMAX];
    __shared__ int hist[256];
    __shared__ int cur[256];
    __shared__ int sb[256];
    __shared__ int scnt;
    const int b = blockIdx.x, t = threadIdx.x;
    if (t < 256) {
        int v = (t < NBK) ? bsum[t] : 0;
        sb[t] = v;
    }
    if (t == 0) scnt = 0;
    if (t < 256) hist[t] = 0;
    __syncthreads();
#pragma unroll
    for (int off = 1; off < 256; off <<= 1) {
        int u = (t >= off && t < 256) ? sb[t - off] : 0;
        __syncthreads();
        if (t < 256) sb[t] += u;
        __syncthreads();
    }
    const int bbase = (b == 0) ? 0 : sb[b - 1];
    if (b == NBK - 1 && t == 0) row_ptr[NN] = sb[NBK - 1];
    for (int blk = t; blk < PB; blk += 512) {
        int cnt = cellcnt[(size_t)b * PB + blk];
        if (cnt) {
            int off = celloff[(size_t)b * PB + blk];
            int base = atomicAdd(&scnt, cnt);
            if (base + cnt <= SEMAX) {
                const unsigned int* pp = pairs + (size_t)blk * EPB + off;
                for (int j = 0; j < cnt; ++j) {
                    unsigned int v = pp[j];
                    sE[base + j] = v;
                    atomicAdd(&hist[v & 255u], 1);
                }
            }
        }
    }
    __syncthreads();
    int h = (t < 256) ? hist[t] : 0;
    if (t < 256) cur[t] = h;
    __syncthreads();
#pragma unroll
    for (int off = 1; off < 256; off <<= 1) {
        int u = (t >= off && t < 256) ? cur[t - off] : 0;
        __syncthreads();
        if (t < 256) cur[t] += u;
        __syncthreads();
    }
    if (t < 256) {
        int node = (b << 8) + t;
        int base = bbase + cur[t] - h;
        if (node < NN) row_ptr[node] = base;
        cur[t] = base;
    }
    __syncthreads();
    int total = min(scnt, SEMAX);
    for (int i = t; i < total; i += 512) {
        unsigned int v = sE[i];
        int pos = atomicAdd(&cur[v & 255u], 1);
        srcs[pos] = (int)(v >> 16);
    }
}

// ---------------------------------------------------------------------------
// Mean aggregation, hi-plane in -> hi-plane out. One wave per node, 8-deep
// load ILP with a masked 8-wide tail.
__global__ void k_agg(const unsigned int* __restrict__ inh, const int* __restrict__ row_ptr,
                      const int* __restrict__ srcs, unsigned int* __restrict__ oh) {
    int node = blockIdx.x * 4 + (threadIdx.x >> 6);
    if (node >= NN) return;
    int lane = threadIdx.x & 63;
    int b = row_ptr[node], e = row_ptr[node + 1];
    float a0 = 0.f, a1 = 0.f;
    int nfull = (e - b) & ~7;
    int i = b;
    for (; i < b + nfull; i += 8) {
        unsigned int p0 = inh[(size_t)srcs[i + 0] * 64 + lane];
        unsigned int p1 = inh[(size_t)srcs[i + 1] * 64 + lane];
        unsigned int p2 = inh[(size_t)srcs[i + 2] * 64 + lane];
        unsigned int p3 = inh[(size_t)srcs[i + 3] * 64 + lane];
        unsigned int p4 = inh[(size_t)srcs[i + 4] * 64 + lane];
        unsigned int p5 = inh[(size_t)srcs[i + 5] * 64 + lane];
        unsigned int p6 = inh[(size_t)srcs[i + 6] * 64 + lane];
        unsigned int p7 = inh[(size_t)srcs[i + 7] * 64 + lane];
        float u0, u1;
        unpack2h(p0, u0, u1); a0 += u0; a1 += u1;
        unpack2h(p1, u0, u1); a0 += u0; a1 += u1;
        unpack2h(p2, u0, u1); a0 += u0; a1 += u1;
        unpack2h(p3, u0, u1); a0 += u0; a1 += u1;
        unpack2h(p4, u0, u1); a0 += u0; a1 += u1;
        unpack2h(p5, u0, u1); a0 += u0; a1 += u1;
        unpack2h(p6, u0, u1); a0 += u0; a1 += u1;
        unpack2h(p7, u0, u1); a0 += u0; a1 += u1;
    }
    int rem = e - i;
    if (rem > 0) {
        unsigned int p[8];
#pragma unroll
        for (int j = 0; j < 8; ++j) {
            int idx = i + j;
            if (idx > e - 1) idx = e - 1;  // clamped (predicated-out below)
            p[j] = inh[(size_t)srcs[idx] * 64 + lane];
        }
#pragma unroll
        for (int j = 0; j < 8; ++j) {
            float u0, u1;
            unpack2h(p[j], u0, u1);
            if (j < rem) { a0 += u0; a1 += u1; }
        }
    }
    int deg = e - b;
    float inv = 1.0f / (float)(deg > 0 ? deg : 1);
    oh[(size_t)node * 64 + lane] = pack2h((_Float16)(a0 * inv), (_Float16)(a1 * inv));
}

// ---------------------------------------------------------------------------
// f16 MFMA GEMM, B (hi only) staged in LDS in fragment layout.
// A: single hi plane (agg for k<128, self for k>=128); one MFMA per (ks,n).
template <int NT, int KPS, bool PACKOUT>
__launch_bounds__(256, 4)
__global__ void k_mfma(const unsigned short* __restrict__ A1h,
                       const unsigned short* __restrict__ A2h,
                       const unsigned short* __restrict__ Bthf,
                       const float* __restrict__ bias, float* __restrict__ outf,
                       unsigned short* __restrict__ outh, const int NC) {
    constexpr int STAGE_ELEMS = KPS * NT * 64 * 8;
    constexpr int STAGE_U4 = STAGE_ELEMS / 8;
    __shared__ unsigned short sBh[STAGE_ELEMS];

    const int tid = threadIdx.x;
    const int wave = tid >> 6, lane = tid & 63;
    const int quad = lane >> 4, mr = lane & 15;
    const int m0 = blockIdx.x * 64 + wave * 16;
    const int row = m0 + mr;
    const bool rok = row < NN;

    f32x4 acc[NT] = {};
    const f16x8 zero = {};

    auto aload = [&](int ks) -> f16x8 {
        const int ko = ((ks * 32) & 127) + quad * 8;
        const unsigned short* base = (ks < 4) ? A1h : A2h;
        return rok ? *(const f16x8*)(base + (size_t)row * 128 + ko) : zero;
    };

    f16x8 cah = aload(0), pah;

#pragma unroll
    for (int s = 0; s < 8 / KPS; ++s) {
        const uint4* gh = (const uint4*)(Bthf + (size_t)s * STAGE_ELEMS);
        uint4* lh = (uint4*)sBh;
        if (s) __syncthreads();
        for (int i = tid; i < STAGE_U4; i += 256) lh[i] = gh[i];
        __syncthreads();

#pragma unroll
        for (int kl = 0; kl < KPS; ++kl) {
            const int ks = s * KPS + kl;
            if (ks < 7) pah = aload(ks + 1);
#pragma unroll
            for (int n = 0; n < NT; ++n) {
                const int fo = ((kl * NT + n) * 64 + lane) * 8;
                f16x8 bh = *(const f16x8*)(sBh + fo);
                acc[n] = __builtin_amdgcn_mfma_f32_16x16x32_f16(cah, bh, acc[n], 0, 0, 0);
            }
            cah = pah;
        }
    }

    // Epilogue. C/D layout: col = lane&15, row = quad*4 + reg.
#pragma unroll
    for (int n = 0; n < NT; ++n) {
        int col = n * 16 + mr;
        float bv = (col < NC) ? bias[col] : 0.f;
#pragma unroll
        for (int r = 0; r < 4; ++r) {
            int orow = m0 + quad * 4 + r;
            if (orow < NN && col < NC) {
                float v = acc[n][r] + bv;
                v = v > 0.f ? v : 0.f;
                if (PACKOUT) {
                    union { _Float16 f; unsigned short u; } ch;
                    ch.f = (_Float16)v;
                    outh[(size_t)orow * 128 + col] = ch.u;
                } else {
                    outf[(size_t)orow * NC + col] = v;
                }
            }
        }
    }
}

// ---------------------------------------------------------------------------
extern "C" void kernel_launch(void* const* d_in, const int* in_sizes, int n_in,
                              void* d_out, int out_size, void* d_ws, size_t ws_size,
                              hipStream_t stream) {
    const float* x    = (const float*)d_in[0];
    const int*   ei   = (const int*)d_in[1];
    const float* w1_l = (const float*)d_in[2];
    const float* w1_r = (const float*)d_in[3];
    const float* b1   = (const float*)d_in[4];
    const float* w2_l = (const float*)d_in[5];
    const float* w2_r = (const float*)d_in[6];
    const float* b2   = (const float*)d_in[7];
    const float* w3_l = (const float*)d_in[8];
    const float* w3_r = (const float*)d_in[9];
    const float* b3   = (const float*)d_in[10];
    float* out = (float*)d_out;

    char* w = (char*)d_ws;
    size_t off = 0;
    auto alloc = [&](size_t bytes) -> void* {
        void* p = w + off;
        off += (bytes + 255) / 256 * 256;
        return p;
    };
    int* row_ptr = (int*)alloc((size_t)(NN + 1) * 4);
    int* srcs    = (int*)alloc((size_t)NE * 4);
    int* cellcnt = (int*)alloc((size_t)NBK * PB * 4);
    int* celloff = (int*)alloc((size_t)NBK * PB * 4);
    int* bsum    = (int*)alloc((size_t)NBK * 4);
    unsigned int* pairs = (unsigned int*)alloc((size_t)PB * EPB * 4);
    unsigned short* xh   = (unsigned short*)alloc((size_t)NN * DD * 2);  // also h2h
    unsigned short* aggh = (unsigned short*)alloc((size_t)NN * DD * 2);
    unsigned short* h1h  = (unsigned short*)alloc((size_t)NN * DD * 2);
    unsigned short* bt1h = (unsigned short*)alloc((size_t)8 * 8 * 64 * 8 * 2);
    unsigned short* bt2h = (unsigned short*)alloc((size_t)8 * 8 * 64 * 8 * 2);
    unsigned short* bt3h = (unsigned short*)alloc((size_t)8 * 3 * 64 * 8 * 2);
    unsigned short* h2h = xh;  // x dead after layer-1 GEMM
    (void)ws_size;

    k_front<<<PB + CVB + WB, 256, 0, stream>>>(ei, cellcnt, celloff, pairs, x, xh,
                                               w1_l, w1_r, w2_l, w2_r, w3_l, w3_r,
                                               bt1h, bt2h, bt3h);
    k_scan_ba<<<NBK, 256, 0, stream>>>(cellcnt, bsum);
    k_fill2<<<NBK, 512, 0, stream>>>(pairs, cellcnt, celloff, bsum, row_ptr, srcs);

    const int gmb = (NN + 63) / 64;   // 782 (GEMM m-blocks)
    const int gab = (NN + 3) / 4;     // 12500 (agg blocks, 4 nodes each)
    // Layer 1
    k_agg<<<gab, 256, 0, stream>>>((const unsigned int*)xh, row_ptr, srcs,
                                   (unsigned int*)aggh);
    k_mfma<8, 4, true><<<gmb, 256, 0, stream>>>(aggh, xh, bt1h, b1,
                                                nullptr, h1h, DD);
    // Layer 2 (h2h aliases xh; x is dead)
    k_agg<<<gab, 256, 0, stream>>>((const unsigned int*)h1h, row_ptr, srcs,
                                   (unsigned int*)aggh);
    k_mfma<8, 4, true><<<gmb, 256, 0, stream>>>(aggh, h1h, bt2h, b2,
                                                nullptr, h2h, DD);
    // Layer 3
    k_agg<<<gab, 256, 0, stream>>>((const unsigned int*)h2h, row_ptr, srcs,
                                   (unsigned int*)aggh);
    k_mfma<3, 4, false><<<gmb, 256, 0, stream>>>(aggh, h2h, bt3h, b3,
                                                 out, nullptr, NCLS);
}